// Round 1
// baseline (164.334 us; speedup 1.0000x reference)
//
#include <hip/hip_runtime.h>

// ContinuousFilterConv on MI355X (gfx950).
// filtered[e,i] = mask_e * ( sum_u h[e,u] * W2[u, i*128+j] + b2[i*128+j] ) * t[e,j]  summed over j
// Implemented as K=160 bf16 MFMA GEMM (h rows extended with mask channel carrying b2)
// fused with the per-edge matvec epilogue + atomic scatter-add.

typedef __attribute__((ext_vector_type(8))) short bf16x8;
typedef __attribute__((ext_vector_type(4))) float f32x4;
typedef __attribute__((ext_vector_type(4))) unsigned int u32x4;

#define NEDGE 8192
#define NNODE 20000
#define NU    128
#define NG    50

// W2frag: [i(128)][nt(8)][ks(5)][lane(64)][8] bf16   = 2,621,440 elems
// Hfrag : [et(512)][ks(5)][lane(64)][8] bf16         = 1,310,720 elems
// tfrag : [et(512)][nt(8)][lane(64)][4] f32          = 1,048,576 elems
#define W2F_ELEMS (128*8*5*64*8)
#define HF_ELEMS  (512*5*64*8)
#define TF_ELEMS  (512*8*64*4)

static __device__ __forceinline__ unsigned short f2bf(float x) {
  unsigned u = __float_as_uint(x);
  u += 0x7FFFu + ((u >> 16) & 1u);          // round-to-nearest-even
  return (unsigned short)(u >> 16);
}
static __device__ __forceinline__ float fsilu(float x) {
  return x / (1.0f + __expf(-x));
}

// ---------------- Phase 0: W2 (+b2) -> bf16 fragment layout -----------------
__global__ __launch_bounds__(256) void k0_w2frag(const float* __restrict__ W2,
                                                 const float* __restrict__ b2,
                                                 unsigned short* __restrict__ w2f) {
  int f  = blockIdx.x * 256 + threadIdx.x;   // frag id, total 128*8*5*64 = 327680
  int l  = f & 63;
  int fk = f >> 6;          // (i*8+nt)*5+ks
  int ks = fk % 5;
  int ibnt = fk / 5;        // i*8+nt
  int nt = ibnt & 7;
  int i  = ibnt >> 3;
  int c  = i * 128 + nt * 16 + (l & 15);     // W2 column
  int kg = l >> 4;
  union { unsigned short s[8]; u32x4 v; } pk;
  if (ks < 4) {
    int u0 = ks * 32 + kg * 8;
#pragma unroll
    for (int j = 0; j < 8; ++j) pk.s[j] = f2bf(W2[(u0 + j) * 16384 + c]);
  } else {
    // virtual K rows 128..159: row 128 = b2, rest zero
#pragma unroll
    for (int j = 0; j < 8; ++j) pk.s[j] = 0;
    if (kg == 0) pk.s[0] = f2bf(b2[c]);
  }
  *((u32x4*)w2f + f) = pk.v;
}

// ---------- Phase 1: per-edge h (masked, bf16 frag) and t = src@Wt ----------
__global__ __launch_bounds__(256) void k1_edge(const float* __restrict__ NF,
                                               const int*   __restrict__ EI,
                                               const float* __restrict__ DI,
                                               const float* __restrict__ W1,
                                               const float* __restrict__ B1,
                                               const float* __restrict__ WT,
                                               unsigned short* __restrict__ hf,
                                               float* __restrict__ tfr) {
  __shared__ float df[16][NG];
  __shared__ float s_mask[16];
  __shared__ float s_src[16][128];
  __shared__ float t_tile[16][132];          // padded: bank stride 4
  __shared__ unsigned short h_tile[16][136]; // padded
  int et  = blockIdx.x;                      // 0..511
  int e0  = et * 16;
  int tid = threadIdx.x;

  // stage Gaussian basis + mask
  for (int idx = tid; idx < 16 * NG; idx += 256) {
    int e = idx / NG, g = idx - e * NG;
    float d = DI[e0 + e];
    float x = d - (float)g * (30.0f / 49.0f);
    df[e][g] = __expf(-10.0f * x * x);
  }
  if (tid < 16) s_mask[tid] = (DI[e0 + tid] <= 8.0f) ? 1.0f : 0.0f;
  // stage gathered source-node features
  for (int idx = tid; idx < 16 * 128; idx += 256) {
    int e = idx >> 7, u = idx & 127;
    int row = EI[e0 + e];                    // edge_indices[0][e]
    s_src[e][u] = NF[row * 128 + u];
  }
  __syncthreads();

  int j  = tid & 127;
  int es = tid >> 7;                         // 0..1 -> edges es*8..es*8+7

  // h = mask * silu(df @ W1 + b1)
  for (int e = es * 8; e < es * 8 + 8; ++e) {
    float acc = B1[j];
    for (int g = 0; g < NG; ++g) acc += df[e][g] * W1[g * 128 + j];
    h_tile[e][j] = f2bf(s_mask[e] * fsilu(acc));
  }
  // t = src @ Wt   (kept f32)
  {
    float acc[8] = {0.f,0.f,0.f,0.f,0.f,0.f,0.f,0.f};
    for (int u = 0; u < 128; ++u) {
      float w = WT[u * 128 + j];
#pragma unroll
      for (int e8 = 0; e8 < 8; ++e8) acc[e8] += s_src[es * 8 + e8][u] * w;
    }
#pragma unroll
    for (int e8 = 0; e8 < 8; ++e8) t_tile[es * 8 + e8][j] = acc[e8];
  }
  __syncthreads();

  // write Hfrag, ks = 0..3 (one 16B frag per thread)
  {
    int ks = tid >> 6;
    int l  = tid & 63;
    int e  = l & 15;
    int u0 = ks * 32 + (l >> 4) * 8;
    union { unsigned short s[8]; u32x4 v; } pk;
#pragma unroll
    for (int jj = 0; jj < 8; ++jj) pk.s[jj] = h_tile[e][u0 + jj];
    *((u32x4*)hf + (et * 5 + ks) * 64 + l) = pk.v;
  }
  // ks = 4: virtual channel u=128 carries mask (multiplies the b2 row)
  if (tid < 64) {
    int l = tid;
    union { unsigned short s[8]; u32x4 v; } pk;
#pragma unroll
    for (int jj = 0; jj < 8; ++jj) pk.s[jj] = 0;
    if ((l >> 4) == 0) pk.s[0] = f2bf(s_mask[l & 15]);
    *((u32x4*)hf + (et * 5 + 4) * 64 + l) = pk.v;
  }
  // write tfrag (epilogue-order f32)
#pragma unroll
  for (int k = 0; k < 2; ++k) {
    int fi = tid * 2 + k;                    // 0..511
    int l  = fi & 63;
    int nt = fi >> 6;
    f32x4 v;
#pragma unroll
    for (int r = 0; r < 4; ++r) v[r] = t_tile[(l >> 4) * 4 + r][nt * 16 + (l & 15)];
    *((f32x4*)tfr + (et * 8 + nt) * 64 + l) = v;
  }
}

// --------- Phase 2: fused  F = Hext @ W2ext  ->  filtered -> scatter --------
__global__ __launch_bounds__(256) void k2_gemm(const unsigned short* __restrict__ w2f,
                                               const unsigned short* __restrict__ hf,
                                               const float* __restrict__ tfr,
                                               const int* __restrict__ EI,
                                               float* __restrict__ msg) {
  int ebk  = blockIdx.x;                     // 0..127 : 64-edge block
  int ib   = blockIdx.y;                     // 0..31
  int wave = threadIdx.x >> 6;
  int lane = threadIdx.x & 63;
  int i    = ib * 4 + wave;                  // output column-block (W2 col group)

  f32x4 acc[4][8];
#pragma unroll
  for (int rt = 0; rt < 4; ++rt)
#pragma unroll
    for (int nt = 0; nt < 8; ++nt) acc[rt][nt] = (f32x4){0.f, 0.f, 0.f, 0.f};

  const bf16x8* w2p = (const bf16x8*)w2f;
  const bf16x8* hfp = (const bf16x8*)hf;

  for (int ks = 0; ks < 5; ++ks) {
    bf16x8 b[8];
    const bf16x8* bp = w2p + (i * 40 + ks) * 64 + lane;
#pragma unroll
    for (int nt = 0; nt < 8; ++nt) b[nt] = bp[nt * 320];
#pragma unroll
    for (int rt = 0; rt < 4; ++rt) {
      int et = ebk * 4 + rt;
      bf16x8 a = hfp[(et * 5 + ks) * 64 + lane];
#pragma unroll
      for (int nt = 0; nt < 8; ++nt)
        acc[rt][nt] = __builtin_amdgcn_mfma_f32_16x16x32_bf16(a, b[nt], acc[rt][nt], 0, 0, 0);
    }
  }

  // epilogue: filtered[e,i] = sum_j F[e, i*128+j] * t[e,j] ; scatter to dst
  const int* dste = EI + NEDGE;
#pragma unroll
  for (int rt = 0; rt < 4; ++rt) {
    int et = ebk * 4 + rt;
    float ps0 = 0.f, ps1 = 0.f, ps2 = 0.f, ps3 = 0.f;
#pragma unroll
    for (int nt = 0; nt < 8; ++nt) {
      f32x4 t4 = *((const f32x4*)tfr + (et * 8 + nt) * 64 + lane);
      ps0 += acc[rt][nt][0] * t4[0];
      ps1 += acc[rt][nt][1] * t4[1];
      ps2 += acc[rt][nt][2] * t4[2];
      ps3 += acc[rt][nt][3] * t4[3];
    }
#pragma unroll
    for (int m = 1; m < 16; m <<= 1) {
      ps0 += __shfl_xor(ps0, m, 64);
      ps1 += __shfl_xor(ps1, m, 64);
      ps2 += __shfl_xor(ps2, m, 64);
      ps3 += __shfl_xor(ps3, m, 64);
    }
    int g = lane >> 4;
    int r = lane & 15;
    if (r < 4) {
      float v = (r == 0) ? ps0 : (r == 1) ? ps1 : (r == 2) ? ps2 : ps3;
      int e = et * 16 + g * 4 + r;
      atomicAdd(msg + dste[e] * 128 + i, v);
    }
  }
}

// ----------------------- Phase 3: out = silu(messages) ----------------------
__global__ __launch_bounds__(256) void k3_silu(float* __restrict__ out, int n4) {
  int idx = blockIdx.x * 256 + threadIdx.x;
  int stride = gridDim.x * 256;
  f32x4* p = (f32x4*)out;
  for (; idx < n4; idx += stride) {
    f32x4 v = p[idx];
#pragma unroll
    for (int c = 0; c < 4; ++c) v[c] = fsilu(v[c]);
    p[idx] = v;
  }
}

extern "C" void kernel_launch(void* const* d_in, const int* in_sizes, int n_in,
                              void* d_out, int out_size, void* d_ws, size_t ws_size,
                              hipStream_t stream) {
  const float* NF = (const float*)d_in[0];
  const int*   EI = (const int*)  d_in[1];
  const float* DI = (const float*)d_in[2];
  const float* W1 = (const float*)d_in[3];
  const float* B1 = (const float*)d_in[4];
  const float* W2 = (const float*)d_in[5];
  const float* B2 = (const float*)d_in[6];
  const float* WT = (const float*)d_in[7];
  float* out = (float*)d_out;

  unsigned short* w2f = (unsigned short*)d_ws;
  unsigned short* hfp = w2f + W2F_ELEMS;
  float*          tfr = (float*)(hfp + HF_ELEMS);
  size_t needed = (size_t)W2F_ELEMS * 2 + (size_t)HF_ELEMS * 2 + (size_t)TF_ELEMS * 4;
  if (ws_size < needed) return;  // insufficient scratch: fail loudly (wrong output)

  hipMemsetAsync(d_out, 0, (size_t)out_size * sizeof(float), stream);
  k0_w2frag<<<dim3(W2F_ELEMS / 8 / 256), dim3(256), 0, stream>>>(W2, B2, w2f);
  k1_edge  <<<dim3(512),                 dim3(256), 0, stream>>>(NF, EI, DI, W1, B1, WT, hfp, tfr);
  k2_gemm  <<<dim3(128, 32),             dim3(256), 0, stream>>>(w2f, hfp, tfr, EI, out);
  k3_silu  <<<dim3(1024),                dim3(256), 0, stream>>>(out, out_size / 4);
}

// Round 2
// 95.614 us; speedup vs baseline: 1.7187x; 1.7187x over previous
//
#include <hip/hip_runtime.h>
#include <hip/hip_fp16.h>

// ContinuousFilterConv on MI355X (gfx950), round 2.
// filtered[e,i] = sum_{u,j} h[e,u] * tm[e,j] * W2ext[u, i*128+j]
// Single GEMM: C[8192 x 128] = A[8192 x 16512] @ B[16512 x 128], f16 MFMA,
// A generated on the fly as outer product h (x) tm. b2 folded as u=128 row
// (h row 128 = 1), cutoff mask folded into tm. K split over 8 u-chunks
// across blocks; scatter-add into messages via atomicAdd (already needed).

typedef _Float16 f16;
typedef __attribute__((ext_vector_type(8))) f16 f16x8;
typedef __attribute__((ext_vector_type(4))) float f32x4;
typedef __attribute__((ext_vector_type(4))) unsigned int u32x4;

#define NEDGE 8192
#define NNODE 20000
#define NG    50
#define KSTEPS 516                       // 129 u-rows * 128 j / 32
#define W2C_BYTES (KSTEPS * 8192)        // 4,227,072  [step][nt8][lane64][8] f16
#define HT_ROWS 132                      // 129 used (row 128 = ones), pad to 132
#define HT_BYTES (HT_ROWS * 8192 * 2)    // 2,162,688  h_t[u][e] f16
#define TM_BYTES (NEDGE * 128 * 2)       // 2,097,152  tm[e][j] f16 (mask folded)

// k2 LDS map (bytes)
#define LDS_H   0                        // 20 rows x 256 B = 5120
#define LDS_TM  5120                     // 128 x 256 B (XOR-swizzled) = 32768
#define LDS_B   37888                    // 2 x 16384 (double-buffered, 2 K-steps each)
#define LDS_TOT 70656

static __device__ __forceinline__ float fsilu(float x) { return x / (1.0f + __expf(-x)); }

static __device__ __forceinline__ void gll16(const void* g, void* l) {
  __builtin_amdgcn_global_load_lds(
      (const __attribute__((address_space(1))) unsigned int*)g,
      (__attribute__((address_space(3))) unsigned int*)l, 16, 0, 0);
}

// ---------------- k0: W2 (+b2) -> f16, MFMA-B fragment-linear per K-step ----
__global__ __launch_bounds__(256) void k0_w2c(const float* __restrict__ W2,
                                              const float* __restrict__ b2,
                                              f16* __restrict__ w2c) {
  int gidx = blockIdx.x * 256 + threadIdx.x;   // 16B-group id, 516*512 = 264192 total
  int lane = gidx & 63;
  int nt   = (gidx >> 6) & 7;
  int step = gidx >> 9;
  int k0i = step * 32 + (lane >> 4) * 8;       // first k of this group
  int i   = nt * 16 + (lane & 15);
  int u   = k0i >> 7, j0 = k0i & 127;
  const float* src = (u < 128) ? (W2 + (size_t)u * 16384 + i * 128 + j0)
                               : (b2 + i * 128 + j0);
  union { f16 s[8]; u32x4 v; } pk;
#pragma unroll
  for (int r = 0; r < 8; ++r) pk.s[r] = (f16)src[r];
  *((u32x4*)w2c + gidx) = pk.v;
}

// ---------------- k1: per-edge h (unmasked) and tm = mask * (src@Wt) -------
__global__ __launch_bounds__(256) void k1_edge(const float* __restrict__ NF,
                                               const int*   __restrict__ EI,
                                               const float* __restrict__ DI,
                                               const float* __restrict__ W1,
                                               const float* __restrict__ B1,
                                               const float* __restrict__ WT,
                                               f16* __restrict__ ht,
                                               f16* __restrict__ tmo) {
  __shared__ float df[16][NG];
  __shared__ float s_mask[16];
  __shared__ float s_src[16][128];
  __shared__ float t_tile[16][132];
  __shared__ float h_tile[16][132];
  int et = blockIdx.x, e0 = et * 16, tid = threadIdx.x;

  for (int idx = tid; idx < 16 * NG; idx += 256) {
    int e = idx / NG, g = idx - e * NG;
    float d = DI[e0 + e];
    float x = d - (float)g * (30.0f / 49.0f);
    df[e][g] = __expf(-10.0f * x * x);
  }
  if (tid < 16) s_mask[tid] = (DI[e0 + tid] <= 8.0f) ? 1.0f : 0.0f;
  for (int idx = tid; idx < 16 * 128; idx += 256) {
    int e = idx >> 7, u = idx & 127;
    s_src[e][u] = NF[(size_t)EI[e0 + e] * 128 + u];
  }
  __syncthreads();

  int j = tid & 127, es = tid >> 7;
  for (int e = es * 8; e < es * 8 + 8; ++e) {
    float acc = B1[j];
    for (int g = 0; g < NG; ++g) acc += df[e][g] * W1[g * 128 + j];
    h_tile[e][j] = fsilu(acc);
  }
  {
    float acc[8] = {0.f,0.f,0.f,0.f,0.f,0.f,0.f,0.f};
    for (int u = 0; u < 128; ++u) {
      float wv = WT[u * 128 + j];
#pragma unroll
      for (int e8 = 0; e8 < 8; ++e8) acc[e8] += s_src[es * 8 + e8][u] * wv;
    }
#pragma unroll
    for (int e8 = 0; e8 < 8; ++e8) t_tile[es * 8 + e8][j] = acc[e8];
  }
  __syncthreads();

  // ht[u][e0..e0+16) : tid -> (u = tid>>1, half = tid&1)
  {
    int u = tid >> 1, hf = tid & 1;
    union { f16 s[8]; u32x4 v; } pk;
#pragma unroll
    for (int k = 0; k < 8; ++k) pk.s[k] = (f16)h_tile[hf * 8 + k][u];
    *(u32x4*)(ht + (size_t)u * 8192 + e0 + hf * 8) = pk.v;
  }
  if (tid < 16) ht[(size_t)128 * 8192 + e0 + tid] = (f16)1.0f;  // ones row (b2 channel)
  // tm[e][j], mask folded: tid -> (e = tid>>4, chunk = tid&15)
  {
    int e = tid >> 4, cc = tid & 15;
    float m = s_mask[e];
    union { f16 s[8]; u32x4 v; } pk;
#pragma unroll
    for (int k = 0; k < 8; ++k) pk.s[k] = (f16)(m * t_tile[e][cc * 8 + k]);
    *(u32x4*)(tmo + (size_t)(e0 + e) * 128 + cc * 8) = pk.v;
  }
}

// ---------------- k2: fused outer-product GEMM + scatter-add ----------------
// grid 512: chunk c = bid&7 (u-range 16, c==7 has 17 incl. b2 row), eb = bid>>3.
// Block: 4 waves, 128 edges x 128 i. Wave: 32e x 128i, acc[2][8] f32x4.
__global__ __launch_bounds__(256, 2) void k2_gemm(const f16* __restrict__ w2c,
                                                  const f16* __restrict__ ht,
                                                  const f16* __restrict__ tm,
                                                  const int* __restrict__ EI,
                                                  float* __restrict__ msg) {
  __shared__ u32x4 smem_v[LDS_TOT / 16];
  char* smem = (char*)smem_v;

  int bid = blockIdx.x;
  int c   = bid & 7;
  int eb  = bid >> 3;
  int e0  = eb * 128;
  int u0  = c * 16;
  int gstep0 = c * 64;
  int nsteps = (c == 7) ? 68 : 64;
  int tid = threadIdx.x, w = tid >> 6, lane = tid & 63;
  int l15 = lane & 15, g4 = lane >> 4;

  // stage h rows (wave 0): 20 rows x 256 B, linear
  if (w == 0) {
#pragma unroll
    for (int q = 0; q < 5; ++q) {
      const char* src = (const char*)ht + ((size_t)(u0 + q * 4 + g4) * 8192 + e0 + l15 * 8) * 2;
      gll16(src, smem + LDS_H + q * 1024 + lane * 16);
    }
  }
  // stage tm (reg-staged, XOR-swizzled): 128 rows x 256 B
#pragma unroll
  for (int it = 0; it < 8; ++it) {
    int ck = it * 256 + tid;                       // 0..2047 16B-chunks
    int e = ck >> 4, jc = ck & 15;
    u32x4 v = *(const u32x4*)((const char*)tm + (size_t)(e0 + e) * 256 + jc * 16);
    *(u32x4*)(smem + LDS_TM + e * 256 + ((jc * 16) ^ ((e & 7) << 4))) = v;
  }
  // stage B phase 0 (2 K-steps = 16 KB)
  const char* bsrc = (const char*)w2c + (size_t)gstep0 * 8192;
#pragma unroll
  for (int q = 0; q < 4; ++q)
    gll16(bsrc + w * 4096 + q * 1024 + lane * 16,
          smem + LDS_B + w * 4096 + q * 1024 + lane * 16);
  asm volatile("s_waitcnt vmcnt(0)" ::: "memory");
  __syncthreads();

  f32x4 acc[2][8];
#pragma unroll
  for (int rt = 0; rt < 2; ++rt)
#pragma unroll
    for (int nt = 0; nt < 8; ++nt) acc[rt][nt] = (f32x4){0.f, 0.f, 0.f, 0.f};

  __half2 hb0 = __half2half2(__half(0.f)), hb1 = hb0;
  const int tmswz = (l15 & 7) << 4;
  const int tma0  = LDS_TM + (w * 32 + l15) * 256;     // rt=0 row base (+4096 for rt=1)
  int nph = nsteps >> 1;

  for (int ph = 0; ph < nph; ++ph) {
    int cur = ph & 1;
    if (ph + 1 < nph) {                         // stage next phase's 2 K-steps
      const char* ns = bsrc + (size_t)(ph + 1) * 16384;
#pragma unroll
      for (int q = 0; q < 4; ++q)
        gll16(ns + w * 4096 + q * 1024 + lane * 16,
              smem + LDS_B + (1 - cur) * 16384 + w * 4096 + q * 1024 + lane * 16);
    }
    if ((ph & 1) == 0) {                        // u advances every 4 K-steps = 2 phases
      int uu = ph >> 1;
      const __half* hrow = (const __half*)(smem + LDS_H + uu * 256);
      hb0 = __half2half2(hrow[w * 32 + l15]);
      hb1 = __half2half2(hrow[w * 32 + 16 + l15]);
    }
#pragma unroll
    for (int s = 0; s < 2; ++s) {
      int s4 = ((ph & 1) << 1) | s;
      int coloff = (s4 * 64 + g4 * 16) ^ tmswz;
      union { f16x8 v; __half2 h2[4]; } t0, t1, a0, a1;
      t0.v = *(const f16x8*)(smem + tma0 + coloff);
      t1.v = *(const f16x8*)(smem + tma0 + 4096 + coloff);
#pragma unroll
      for (int q = 0; q < 4; ++q) {
        a0.h2[q] = __hmul2(t0.h2[q], hb0);
        a1.h2[q] = __hmul2(t1.h2[q], hb1);
      }
      const char* bb = smem + LDS_B + cur * 16384 + s * 8192 + lane * 16;
#pragma unroll
      for (int nt = 0; nt < 8; ++nt) {
        f16x8 b = *(const f16x8*)(bb + nt * 1024);
        acc[0][nt] = __builtin_amdgcn_mfma_f32_16x16x32_f16(a0.v, b, acc[0][nt], 0, 0, 0);
        acc[1][nt] = __builtin_amdgcn_mfma_f32_16x16x32_f16(a1.v, b, acc[1][nt], 0, 0, 0);
      }
    }
    asm volatile("s_waitcnt vmcnt(0)" ::: "memory");
    __syncthreads();
  }

  // epilogue: scatter-add partials
  const int* dst = EI + NEDGE;
  int erow = e0 + w * 32;
#pragma unroll
  for (int rt = 0; rt < 2; ++rt)
#pragma unroll
    for (int r = 0; r < 4; ++r) {
      int e = erow + rt * 16 + g4 * 4 + r;
      float* row = msg + (size_t)dst[e] * 128 + l15;
#pragma unroll
      for (int nt = 0; nt < 8; ++nt)
        atomicAdd(row + nt * 16, acc[rt][nt][r]);
    }
}

// ---------------- k3: out = silu(messages) ----------------------------------
__global__ __launch_bounds__(256) void k3_silu(float* __restrict__ out, int n4) {
  int idx = blockIdx.x * 256 + threadIdx.x;
  int stride = gridDim.x * 256;
  f32x4* p = (f32x4*)out;
  for (; idx < n4; idx += stride) {
    f32x4 v = p[idx];
#pragma unroll
    for (int cc = 0; cc < 4; ++cc) v[cc] = fsilu(v[cc]);
    p[idx] = v;
  }
}

extern "C" void kernel_launch(void* const* d_in, const int* in_sizes, int n_in,
                              void* d_out, int out_size, void* d_ws, size_t ws_size,
                              hipStream_t stream) {
  const float* NF = (const float*)d_in[0];
  const int*   EI = (const int*)  d_in[1];
  const float* DI = (const float*)d_in[2];
  const float* W1 = (const float*)d_in[3];
  const float* B1 = (const float*)d_in[4];
  const float* W2 = (const float*)d_in[5];
  const float* B2 = (const float*)d_in[6];
  const float* WT = (const float*)d_in[7];
  float* out = (float*)d_out;

  f16* w2c = (f16*)d_ws;
  f16* ht  = (f16*)((char*)d_ws + W2C_BYTES);
  f16* tmo = (f16*)((char*)d_ws + W2C_BYTES + HT_BYTES);
  size_t needed = (size_t)W2C_BYTES + HT_BYTES + TM_BYTES;
  if (ws_size < needed) return;  // insufficient scratch: fail loudly

  hipMemsetAsync(d_out, 0, (size_t)out_size * sizeof(float), stream);
  k0_w2c <<<dim3(1032), dim3(256), 0, stream>>>(W2, B2, w2c);
  k1_edge<<<dim3(512),  dim3(256), 0, stream>>>(NF, EI, DI, W1, B1, WT, ht, tmo);
  k2_gemm<<<dim3(512),  dim3(256), 0, stream>>>(w2c, ht, tmo, EI, out);
  k3_silu<<<dim3(1024), dim3(256), 0, stream>>>(out, out_size / 4);
}